// Round 2
// baseline (1495.626 us; speedup 1.0000x reference)
//
#include <hip/hip_runtime.h>
#include <cstdint>
#include <cstddef>

// ---------------------------------------------------------------------------
// WindowGCN: 2-layer GCN + mean-pool + linear head, all fp32.
//   h1 = relu((A_hat @ x) @ W1 + b1)      (aggregate-first: A_hat linear)
//   h2 = relu((A_hat @ h1) @ W2 + b2)
//   out = mean_pool(h2, batch) @ Wc + bc
// A_hat = D^-1/2 (A + I) D^-1/2, aggregation via per-call CSR (atomic-free).
// ---------------------------------------------------------------------------

__global__ __launch_bounds__(256) void deg_count_kernel(const int* __restrict__ dst,
                                                        int* __restrict__ deg, int E) {
    int e = blockIdx.x * 256 + threadIdx.x;
    if (e < E) atomicAdd(&deg[dst[e]], 1);
}

__global__ __launch_bounds__(256) void graph_count_kernel(const int* __restrict__ batch,
                                                          int* __restrict__ cnt, int N) {
    int n = blockIdx.x * 256 + threadIdx.x;
    if (n < N) atomicAdd(&cnt[batch[n]], 1);
}

__global__ __launch_bounds__(256) void dinv_kernel(const int* __restrict__ deg,
                                                   float* __restrict__ dinv, int N) {
    int n = blockIdx.x * 256 + threadIdx.x;
    if (n < N) dinv[n] = rsqrtf((float)deg[n] + 1.0f);  // +1 self-loop; always > 0
}

// Single-block exclusive scan of deg[0..N) -> off[0..N], 1024 threads,
// 4 elements/thread/chunk, wave shuffle scan + cross-wave LDS scan.
__global__ __launch_bounds__(1024) void scan_kernel(const int* __restrict__ deg,
                                                    int* __restrict__ off, int N) {
    __shared__ int wsum[16];
    __shared__ int carry_s;
    int t = threadIdx.x, lane = t & 63, w = t >> 6;
    if (t == 0) { carry_s = 0; off[0] = 0; }
    __syncthreads();
    for (int base = 0; base < N; base += 4096) {
        int idx = base + t * 4;
        int v0 = (idx + 0 < N) ? deg[idx + 0] : 0;
        int v1 = (idx + 1 < N) ? deg[idx + 1] : 0;
        int v2 = (idx + 2 < N) ? deg[idx + 2] : 0;
        int v3 = (idx + 3 < N) ? deg[idx + 3] : 0;
        int i0 = v0, i1 = i0 + v1, i2 = i1 + v2, i3 = i2 + v3;
        int x = i3;
        #pragma unroll
        for (int d = 1; d < 64; d <<= 1) {
            int y = __shfl_up(x, d, 64);
            if (lane >= d) x += y;
        }
        if (lane == 63) wsum[w] = x;
        __syncthreads();
        int woff = 0;
        #pragma unroll
        for (int j = 0; j < 16; j++)
            if (j < w) woff += wsum[j];
        int c = carry_s;
        __syncthreads();
        int pre = c + woff + (x - i3);  // exclusive prefix before idx
        if (idx + 0 < N) off[idx + 1] = pre + i0;
        if (idx + 1 < N) off[idx + 2] = pre + i1;
        if (idx + 2 < N) off[idx + 3] = pre + i2;
        if (idx + 3 < N) off[idx + 4] = pre + i3;
        if (t == 1023) carry_s = pre + i3;  // chunk total
        __syncthreads();
    }
}

__global__ __launch_bounds__(256) void csr_fill_kernel(const int* __restrict__ src,
                                                       const int* __restrict__ dst,
                                                       const int* __restrict__ off,
                                                       int* __restrict__ cursor,
                                                       int* __restrict__ csr, int E) {
    int e = blockIdx.x * 256 + threadIdx.x;
    if (e < E) {
        int d = dst[e];
        int p = off[d] + atomicAdd(&cursor[d], 1);
        csr[p] = src[e];
    }
}

// OUT[i] = dinv[i] * ( dinv[i]*X[i] + sum_{s in in(i)} dinv[s]*X[s] )
// One wave per node; lane owns VEC consecutive columns (F = VEC*64).
template <int VEC>
__global__ __launch_bounds__(256) void aggregate_kernel(const float* __restrict__ X,
                                                        float* __restrict__ OUT,
                                                        const int* __restrict__ off,
                                                        const int* __restrict__ csr,
                                                        const float* __restrict__ dinv, int N) {
    constexpr int F = VEC * 64;
    int w = threadIdx.x >> 6, lane = threadIdx.x & 63;
    int node = blockIdx.x * 4 + w;
    if (node >= N) return;
    float di = dinv[node];
    float acc[VEC];
    if constexpr (VEC == 4) {
        float4 xv = *reinterpret_cast<const float4*>(X + (size_t)node * F + lane * 4);
        acc[0] = di * xv.x; acc[1] = di * xv.y; acc[2] = di * xv.z; acc[3] = di * xv.w;
    } else {
        float2 xv = *reinterpret_cast<const float2*>(X + (size_t)node * F + lane * 2);
        acc[0] = di * xv.x; acc[1] = di * xv.y;
    }
    int e0 = off[node], e1 = off[node + 1];
    for (int e = e0; e < e1; e++) {
        int s = csr[e];
        float ds = dinv[s];
        if constexpr (VEC == 4) {
            float4 xv = *reinterpret_cast<const float4*>(X + (size_t)s * F + lane * 4);
            acc[0] += ds * xv.x; acc[1] += ds * xv.y; acc[2] += ds * xv.z; acc[3] += ds * xv.w;
        } else {
            float2 xv = *reinterpret_cast<const float2*>(X + (size_t)s * F + lane * 2);
            acc[0] += ds * xv.x; acc[1] += ds * xv.y;
        }
    }
    if constexpr (VEC == 4) {
        float4 o = make_float4(di * acc[0], di * acc[1], di * acc[2], di * acc[3]);
        *reinterpret_cast<float4*>(OUT + (size_t)node * F + lane * 4) = o;
    } else {
        float2 o = make_float2(di * acc[0], di * acc[1]);
        *reinterpret_cast<float2*>(OUT + (size_t)node * F + lane * 2) = o;
    }
}

// C[M][256] = relu(A[M][K] @ W[K][256] + bias). Tile: 64 rows x 256 cols,
// 256 threads, each thread 16 rows x 4 cols in registers. K % 32 == 0.
__global__ __launch_bounds__(256) void gemm_bias_relu_kernel(const float* __restrict__ A,
                                                             const float* __restrict__ W,
                                                             const float* __restrict__ bias,
                                                             float* __restrict__ C, int M, int K) {
    __shared__ __align__(16) float As[32 * 68];   // [kk][row], stride 68 (pad, 16B-aligned)
    __shared__ __align__(16) float Ws[32 * 256];  // [kk][col]
    int t = threadIdx.x;
    int lane = t & 63, w = t >> 6;
    int r0 = blockIdx.x * 64;
    int col = lane * 4;
    float4 acc[16];
    #pragma unroll
    for (int i = 0; i < 16; i++) acc[i] = make_float4(0.f, 0.f, 0.f, 0.f);
    int fA = t & 7, rA = t >> 3;          // A-staging: 8 float4 per row chunk
    int cW = (t & 63) * 4, kW = t >> 6;   // W-staging

    for (int k0 = 0; k0 < K; k0 += 32) {
        #pragma unroll
        for (int p = 0; p < 2; p++) {
            int r = rA + 32 * p;
            int grow = r0 + r;
            float4 v = make_float4(0.f, 0.f, 0.f, 0.f);
            if (grow < M) v = *reinterpret_cast<const float4*>(A + (size_t)grow * K + k0 + 4 * fA);
            As[(4 * fA + 0) * 68 + r] = v.x;
            As[(4 * fA + 1) * 68 + r] = v.y;
            As[(4 * fA + 2) * 68 + r] = v.z;
            As[(4 * fA + 3) * 68 + r] = v.w;
        }
        #pragma unroll
        for (int p = 0; p < 8; p++) {
            int kk = kW + 4 * p;
            *reinterpret_cast<float4*>(Ws + kk * 256 + cW) =
                *reinterpret_cast<const float4*>(W + (size_t)(k0 + kk) * 256 + cW);
        }
        __syncthreads();
        #pragma unroll 8
        for (int kk = 0; kk < 32; kk++) {
            float4 wv = *reinterpret_cast<const float4*>(Ws + kk * 256 + col);
            const float4* ap = reinterpret_cast<const float4*>(As + kk * 68 + 16 * w);
            #pragma unroll
            for (int j = 0; j < 4; j++) {
                float4 av = ap[j];
                acc[4 * j + 0].x += av.x * wv.x; acc[4 * j + 0].y += av.x * wv.y;
                acc[4 * j + 0].z += av.x * wv.z; acc[4 * j + 0].w += av.x * wv.w;
                acc[4 * j + 1].x += av.y * wv.x; acc[4 * j + 1].y += av.y * wv.y;
                acc[4 * j + 1].z += av.y * wv.z; acc[4 * j + 1].w += av.y * wv.w;
                acc[4 * j + 2].x += av.z * wv.x; acc[4 * j + 2].y += av.z * wv.y;
                acc[4 * j + 2].z += av.z * wv.z; acc[4 * j + 2].w += av.z * wv.w;
                acc[4 * j + 3].x += av.w * wv.x; acc[4 * j + 3].y += av.w * wv.y;
                acc[4 * j + 3].z += av.w * wv.z; acc[4 * j + 3].w += av.w * wv.w;
            }
        }
        __syncthreads();
    }
    float4 b4 = *reinterpret_cast<const float4*>(bias + col);
    #pragma unroll
    for (int j = 0; j < 16; j++) {
        int grow = r0 + 16 * w + j;
        if (grow < M) {
            float4 o = acc[j];
            o.x = fmaxf(o.x + b4.x, 0.f);
            o.y = fmaxf(o.y + b4.y, 0.f);
            o.z = fmaxf(o.z + b4.z, 0.f);
            o.w = fmaxf(o.w + b4.w, 0.f);
            *reinterpret_cast<float4*>(C + (size_t)grow * 256 + col) = o;
        }
    }
}

// Segment-sum over sorted batch: block handles 256 consecutive nodes, thread t
// owns column t; run-length accumulate, flush on batch change (few atomics).
__global__ __launch_bounds__(256) void pool_partial_kernel(const float* __restrict__ H,
                                                           const int* __restrict__ batch,
                                                           float* __restrict__ gsum, int N) {
    int t = threadIdx.x;
    int n0 = blockIdx.x * 256;
    int nend = min(n0 + 256, N);
    int cur = batch[n0];
    float acc = 0.f;
    for (int n = n0; n < nend; n++) {
        int b = batch[n];
        if (b != cur) {
            atomicAdd(&gsum[cur * 256 + t], acc);
            acc = 0.f;
            cur = b;
        }
        acc += H[(size_t)n * 256 + t];
    }
    atomicAdd(&gsum[cur * 256 + t], acc);
}

// out[g][c] = sum_k (gsum[g][k]/max(cnt,1)) * Wc[k][c] + bc[c];  one block/graph
__global__ __launch_bounds__(256) void pool_final_kernel(const float* __restrict__ gsum,
                                                         const int* __restrict__ cnt,
                                                         const float* __restrict__ Wc,
                                                         const float* __restrict__ bc,
                                                         float* __restrict__ out) {
    __shared__ float gm[256];
    int g = blockIdx.x, t = threadIdx.x;
    float inv = 1.0f / fmaxf((float)cnt[g], 1.0f);
    gm[t] = gsum[g * 256 + t] * inv;
    __syncthreads();
    if (t < 200) {
        float acc = bc[t];
        #pragma unroll 8
        for (int k = 0; k < 256; k++) acc += gm[k] * Wc[k * 200 + t];
        out[g * 200 + t] = acc;
    }
}

extern "C" void kernel_launch(void* const* d_in, const int* in_sizes, int n_in,
                              void* d_out, int out_size, void* d_ws, size_t ws_size,
                              hipStream_t stream) {
    const float* x   = (const float*)d_in[0];
    const int* ei    = (const int*)d_in[1];
    const int* batch = (const int*)d_in[2];
    const float* W1  = (const float*)d_in[4];
    const float* b1  = (const float*)d_in[5];
    const float* W2  = (const float*)d_in[6];
    const float* b2  = (const float*)d_in[7];
    const float* Wc  = (const float*)d_in[8];
    const float* bc  = (const float*)d_in[9];
    float* out = (float*)d_out;

    const int N = in_sizes[2];       // 100000 nodes
    const int E = in_sizes[1] / 2;   // 1600000 edges
    const int G = out_size / 200;    // 64 graphs
    const int K1 = in_sizes[0] / N;  // 128
    const int* src = ei;
    const int* dst = ei + E;

    // workspace carve-out (~213 MB)
    char* p = (char*)d_ws;
    auto alloc = [&](size_t bytes) -> char* {
        char* r = p;
        p += (bytes + 255) & ~(size_t)255;
        return r;
    };
    int*   off    = (int*)alloc((size_t)(N + 1) * 4);
    int*   deg    = (int*)alloc((size_t)N * 4);
    int*   cursor = (int*)alloc((size_t)N * 4);
    int*   cnt    = (int*)alloc(256 * 4);
    float* dinv   = (float*)alloc((size_t)N * 4);
    float* gsum   = (float*)alloc((size_t)G * 256 * 4);
    int*   csr    = (int*)alloc((size_t)E * 4);
    float* bufA   = (float*)alloc((size_t)N * 256 * 4);
    float* bufB   = (float*)alloc((size_t)N * 256 * 4);

    hipMemsetAsync(deg, 0, (size_t)N * 4, stream);
    hipMemsetAsync(cursor, 0, (size_t)N * 4, stream);
    hipMemsetAsync(cnt, 0, 256 * 4, stream);
    hipMemsetAsync(gsum, 0, (size_t)G * 256 * 4, stream);

    int blkE = (E + 255) / 256, blkN = (N + 255) / 256;
    deg_count_kernel<<<blkE, 256, 0, stream>>>(dst, deg, E);
    graph_count_kernel<<<blkN, 256, 0, stream>>>(batch, cnt, N);
    dinv_kernel<<<blkN, 256, 0, stream>>>(deg, dinv, N);
    scan_kernel<<<1, 1024, 0, stream>>>(deg, off, N);
    csr_fill_kernel<<<blkE, 256, 0, stream>>>(src, dst, off, cursor, csr, E);

    // layer 1: aggregate-first (128-dim), then GEMM(+bias+relu) to 256
    aggregate_kernel<2><<<(N + 3) / 4, 256, 0, stream>>>(x, bufA, off, csr, dinv, N);
    gemm_bias_relu_kernel<<<(N + 63) / 64, 256, 0, stream>>>(bufA, W1, b1, bufB, N, K1);
    // layer 2
    aggregate_kernel<4><<<(N + 3) / 4, 256, 0, stream>>>(bufB, bufA, off, csr, dinv, N);
    gemm_bias_relu_kernel<<<(N + 63) / 64, 256, 0, stream>>>(bufA, W2, b2, bufB, N, 256);
    // mean-pool + classifier head
    pool_partial_kernel<<<blkN, 256, 0, stream>>>(bufB, batch, gsum, N);
    pool_final_kernel<<<G, 256, 0, stream>>>(gsum, cnt, Wc, bc, out);
}

// Round 3
// 992.353 us; speedup vs baseline: 1.5072x; 1.5072x over previous
//
#include <hip/hip_runtime.h>
#include <cstdint>
#include <cstddef>

// ---------------------------------------------------------------------------
// WindowGCN: 2-layer GCN + mean-pool + linear head, all fp32.
//   h1 = relu((A_hat @ x) @ W1 + b1)      (aggregate-first: A_hat linear)
//   h2 = relu((A_hat @ h1) @ W2 + b2)
//   out = mean_pool(h2, batch) @ Wc + bc
// A_hat = D^-1/2 (A + I) D^-1/2, aggregation via per-call CSR (atomic-free).
// R3: graph_count via per-block LDS histogram (was 510us of global-atomic
//     contention on 64 addresses -- 34% of total).
// ---------------------------------------------------------------------------

__global__ __launch_bounds__(256) void deg_count_kernel(const int* __restrict__ dst,
                                                        int* __restrict__ deg, int E) {
    int e = blockIdx.x * 256 + threadIdx.x;
    if (e < E) atomicAdd(&deg[dst[e]], 1);
}

// Histogram of batch ids (G <= 256) via LDS bins: one global atomic per
// (block, nonempty bin) instead of one per node.
__global__ __launch_bounds__(256) void graph_count_kernel(const int* __restrict__ batch,
                                                          int* __restrict__ cnt, int N) {
    __shared__ int h[256];
    int t = threadIdx.x;
    h[t] = 0;
    __syncthreads();
    int n = blockIdx.x * 256 + t;
    if (n < N) atomicAdd(&h[batch[n]], 1);
    __syncthreads();
    if (h[t] != 0) atomicAdd(&cnt[t], h[t]);
}

__global__ __launch_bounds__(256) void dinv_kernel(const int* __restrict__ deg,
                                                   float* __restrict__ dinv, int N) {
    int n = blockIdx.x * 256 + threadIdx.x;
    if (n < N) dinv[n] = rsqrtf((float)deg[n] + 1.0f);  // +1 self-loop; always > 0
}

// Single-block exclusive scan of deg[0..N) -> off[0..N], 1024 threads,
// 4 elements/thread/chunk, wave shuffle scan + cross-wave LDS scan.
__global__ __launch_bounds__(1024) void scan_kernel(const int* __restrict__ deg,
                                                    int* __restrict__ off, int N) {
    __shared__ int wsum[16];
    __shared__ int carry_s;
    int t = threadIdx.x, lane = t & 63, w = t >> 6;
    if (t == 0) { carry_s = 0; off[0] = 0; }
    __syncthreads();
    for (int base = 0; base < N; base += 4096) {
        int idx = base + t * 4;
        int v0 = (idx + 0 < N) ? deg[idx + 0] : 0;
        int v1 = (idx + 1 < N) ? deg[idx + 1] : 0;
        int v2 = (idx + 2 < N) ? deg[idx + 2] : 0;
        int v3 = (idx + 3 < N) ? deg[idx + 3] : 0;
        int i0 = v0, i1 = i0 + v1, i2 = i1 + v2, i3 = i2 + v3;
        int x = i3;
        #pragma unroll
        for (int d = 1; d < 64; d <<= 1) {
            int y = __shfl_up(x, d, 64);
            if (lane >= d) x += y;
        }
        if (lane == 63) wsum[w] = x;
        __syncthreads();
        int woff = 0;
        #pragma unroll
        for (int j = 0; j < 16; j++)
            if (j < w) woff += wsum[j];
        int c = carry_s;
        __syncthreads();
        int pre = c + woff + (x - i3);  // exclusive prefix before idx
        if (idx + 0 < N) off[idx + 1] = pre + i0;
        if (idx + 1 < N) off[idx + 2] = pre + i1;
        if (idx + 2 < N) off[idx + 3] = pre + i2;
        if (idx + 3 < N) off[idx + 4] = pre + i3;
        if (t == 1023) carry_s = pre + i3;  // chunk total
        __syncthreads();
    }
}

__global__ __launch_bounds__(256) void csr_fill_kernel(const int* __restrict__ src,
                                                       const int* __restrict__ dst,
                                                       const int* __restrict__ off,
                                                       int* __restrict__ cursor,
                                                       int* __restrict__ csr, int E) {
    int e = blockIdx.x * 256 + threadIdx.x;
    if (e < E) {
        int d = dst[e];
        int p = off[d] + atomicAdd(&cursor[d], 1);
        csr[p] = src[e];
    }
}

// OUT[i] = dinv[i] * ( dinv[i]*X[i] + sum_{s in in(i)} dinv[s]*X[s] )
// One wave per node; lane owns VEC consecutive columns (F = VEC*64).
template <int VEC>
__global__ __launch_bounds__(256) void aggregate_kernel(const float* __restrict__ X,
                                                        float* __restrict__ OUT,
                                                        const int* __restrict__ off,
                                                        const int* __restrict__ csr,
                                                        const float* __restrict__ dinv, int N) {
    constexpr int F = VEC * 64;
    int w = threadIdx.x >> 6, lane = threadIdx.x & 63;
    int node = blockIdx.x * 4 + w;
    if (node >= N) return;
    float di = dinv[node];
    float acc[VEC];
    if constexpr (VEC == 4) {
        float4 xv = *reinterpret_cast<const float4*>(X + (size_t)node * F + lane * 4);
        acc[0] = di * xv.x; acc[1] = di * xv.y; acc[2] = di * xv.z; acc[3] = di * xv.w;
    } else {
        float2 xv = *reinterpret_cast<const float2*>(X + (size_t)node * F + lane * 2);
        acc[0] = di * xv.x; acc[1] = di * xv.y;
    }
    int e0 = off[node], e1 = off[node + 1];
    for (int e = e0; e < e1; e++) {
        int s = csr[e];
        float ds = dinv[s];
        if constexpr (VEC == 4) {
            float4 xv = *reinterpret_cast<const float4*>(X + (size_t)s * F + lane * 4);
            acc[0] += ds * xv.x; acc[1] += ds * xv.y; acc[2] += ds * xv.z; acc[3] += ds * xv.w;
        } else {
            float2 xv = *reinterpret_cast<const float2*>(X + (size_t)s * F + lane * 2);
            acc[0] += ds * xv.x; acc[1] += ds * xv.y;
        }
    }
    if constexpr (VEC == 4) {
        float4 o = make_float4(di * acc[0], di * acc[1], di * acc[2], di * acc[3]);
        *reinterpret_cast<float4*>(OUT + (size_t)node * F + lane * 4) = o;
    } else {
        float2 o = make_float2(di * acc[0], di * acc[1]);
        *reinterpret_cast<float2*>(OUT + (size_t)node * F + lane * 2) = o;
    }
}

// C[M][256] = relu(A[M][K] @ W[K][256] + bias). Tile: 64 rows x 256 cols,
// 256 threads, each thread 16 rows x 4 cols in registers. K % 32 == 0.
__global__ __launch_bounds__(256) void gemm_bias_relu_kernel(const float* __restrict__ A,
                                                             const float* __restrict__ W,
                                                             const float* __restrict__ bias,
                                                             float* __restrict__ C, int M, int K) {
    __shared__ __align__(16) float As[32 * 68];   // [kk][row], stride 68 (pad, 16B-aligned)
    __shared__ __align__(16) float Ws[32 * 256];  // [kk][col]
    int t = threadIdx.x;
    int lane = t & 63, w = t >> 6;
    int r0 = blockIdx.x * 64;
    int col = lane * 4;
    float4 acc[16];
    #pragma unroll
    for (int i = 0; i < 16; i++) acc[i] = make_float4(0.f, 0.f, 0.f, 0.f);
    int fA = t & 7, rA = t >> 3;          // A-staging: 8 float4 per row chunk
    int cW = (t & 63) * 4, kW = t >> 6;   // W-staging

    for (int k0 = 0; k0 < K; k0 += 32) {
        #pragma unroll
        for (int p = 0; p < 2; p++) {
            int r = rA + 32 * p;
            int grow = r0 + r;
            float4 v = make_float4(0.f, 0.f, 0.f, 0.f);
            if (grow < M) v = *reinterpret_cast<const float4*>(A + (size_t)grow * K + k0 + 4 * fA);
            As[(4 * fA + 0) * 68 + r] = v.x;
            As[(4 * fA + 1) * 68 + r] = v.y;
            As[(4 * fA + 2) * 68 + r] = v.z;
            As[(4 * fA + 3) * 68 + r] = v.w;
        }
        #pragma unroll
        for (int p = 0; p < 8; p++) {
            int kk = kW + 4 * p;
            *reinterpret_cast<float4*>(Ws + kk * 256 + cW) =
                *reinterpret_cast<const float4*>(W + (size_t)(k0 + kk) * 256 + cW);
        }
        __syncthreads();
        #pragma unroll 8
        for (int kk = 0; kk < 32; kk++) {
            float4 wv = *reinterpret_cast<const float4*>(Ws + kk * 256 + col);
            const float4* ap = reinterpret_cast<const float4*>(As + kk * 68 + 16 * w);
            #pragma unroll
            for (int j = 0; j < 4; j++) {
                float4 av = ap[j];
                acc[4 * j + 0].x += av.x * wv.x; acc[4 * j + 0].y += av.x * wv.y;
                acc[4 * j + 0].z += av.x * wv.z; acc[4 * j + 0].w += av.x * wv.w;
                acc[4 * j + 1].x += av.y * wv.x; acc[4 * j + 1].y += av.y * wv.y;
                acc[4 * j + 1].z += av.y * wv.z; acc[4 * j + 1].w += av.y * wv.w;
                acc[4 * j + 2].x += av.z * wv.x; acc[4 * j + 2].y += av.z * wv.y;
                acc[4 * j + 2].z += av.z * wv.z; acc[4 * j + 2].w += av.z * wv.w;
                acc[4 * j + 3].x += av.w * wv.x; acc[4 * j + 3].y += av.w * wv.y;
                acc[4 * j + 3].z += av.w * wv.z; acc[4 * j + 3].w += av.w * wv.w;
            }
        }
        __syncthreads();
    }
    float4 b4 = *reinterpret_cast<const float4*>(bias + col);
    #pragma unroll
    for (int j = 0; j < 16; j++) {
        int grow = r0 + 16 * w + j;
        if (grow < M) {
            float4 o = acc[j];
            o.x = fmaxf(o.x + b4.x, 0.f);
            o.y = fmaxf(o.y + b4.y, 0.f);
            o.z = fmaxf(o.z + b4.z, 0.f);
            o.w = fmaxf(o.w + b4.w, 0.f);
            *reinterpret_cast<float4*>(C + (size_t)grow * 256 + col) = o;
        }
    }
}

// Segment-sum over sorted batch: block handles 256 consecutive nodes, thread t
// owns column t; run-length accumulate, flush on batch change (few atomics).
__global__ __launch_bounds__(256) void pool_partial_kernel(const float* __restrict__ H,
                                                           const int* __restrict__ batch,
                                                           float* __restrict__ gsum, int N) {
    int t = threadIdx.x;
    int n0 = blockIdx.x * 256;
    int nend = min(n0 + 256, N);
    int cur = batch[n0];
    float acc = 0.f;
    for (int n = n0; n < nend; n++) {
        int b = batch[n];
        if (b != cur) {
            atomicAdd(&gsum[cur * 256 + t], acc);
            acc = 0.f;
            cur = b;
        }
        acc += H[(size_t)n * 256 + t];
    }
    atomicAdd(&gsum[cur * 256 + t], acc);
}

// out[g][c] = sum_k (gsum[g][k]/max(cnt,1)) * Wc[k][c] + bc[c];  one block/graph
__global__ __launch_bounds__(256) void pool_final_kernel(const float* __restrict__ gsum,
                                                         const int* __restrict__ cnt,
                                                         const float* __restrict__ Wc,
                                                         const float* __restrict__ bc,
                                                         float* __restrict__ out) {
    __shared__ float gm[256];
    int g = blockIdx.x, t = threadIdx.x;
    float inv = 1.0f / fmaxf((float)cnt[g], 1.0f);
    gm[t] = gsum[g * 256 + t] * inv;
    __syncthreads();
    if (t < 200) {
        float acc = bc[t];
        #pragma unroll 8
        for (int k = 0; k < 256; k++) acc += gm[k] * Wc[k * 200 + t];
        out[g * 200 + t] = acc;
    }
}

extern "C" void kernel_launch(void* const* d_in, const int* in_sizes, int n_in,
                              void* d_out, int out_size, void* d_ws, size_t ws_size,
                              hipStream_t stream) {
    const float* x   = (const float*)d_in[0];
    const int* ei    = (const int*)d_in[1];
    const int* batch = (const int*)d_in[2];
    const float* W1  = (const float*)d_in[4];
    const float* b1  = (const float*)d_in[5];
    const float* W2  = (const float*)d_in[6];
    const float* b2  = (const float*)d_in[7];
    const float* Wc  = (const float*)d_in[8];
    const float* bc  = (const float*)d_in[9];
    float* out = (float*)d_out;

    const int N = in_sizes[2];       // 100000 nodes
    const int E = in_sizes[1] / 2;   // 1600000 edges
    const int G = out_size / 200;    // 64 graphs
    const int K1 = in_sizes[0] / N;  // 128
    const int* src = ei;
    const int* dst = ei + E;

    // workspace carve-out (~213 MB)
    char* p = (char*)d_ws;
    auto alloc = [&](size_t bytes) -> char* {
        char* r = p;
        p += (bytes + 255) & ~(size_t)255;
        return r;
    };
    int*   off    = (int*)alloc((size_t)(N + 1) * 4);
    int*   deg    = (int*)alloc((size_t)N * 4);
    int*   cursor = (int*)alloc((size_t)N * 4);
    int*   cnt    = (int*)alloc(256 * 4);
    float* dinv   = (float*)alloc((size_t)N * 4);
    float* gsum   = (float*)alloc((size_t)G * 256 * 4);
    int*   csr    = (int*)alloc((size_t)E * 4);
    float* bufA   = (float*)alloc((size_t)N * 256 * 4);
    float* bufB   = (float*)alloc((size_t)N * 256 * 4);

    hipMemsetAsync(deg, 0, (size_t)N * 4, stream);
    hipMemsetAsync(cursor, 0, (size_t)N * 4, stream);
    hipMemsetAsync(cnt, 0, 256 * 4, stream);
    hipMemsetAsync(gsum, 0, (size_t)G * 256 * 4, stream);

    int blkE = (E + 255) / 256, blkN = (N + 255) / 256;
    deg_count_kernel<<<blkE, 256, 0, stream>>>(dst, deg, E);
    graph_count_kernel<<<blkN, 256, 0, stream>>>(batch, cnt, N);
    dinv_kernel<<<blkN, 256, 0, stream>>>(deg, dinv, N);
    scan_kernel<<<1, 1024, 0, stream>>>(deg, off, N);
    csr_fill_kernel<<<blkE, 256, 0, stream>>>(src, dst, off, cursor, csr, E);

    // layer 1: aggregate-first (128-dim), then GEMM(+bias+relu) to 256
    aggregate_kernel<2><<<(N + 3) / 4, 256, 0, stream>>>(x, bufA, off, csr, dinv, N);
    gemm_bias_relu_kernel<<<(N + 63) / 64, 256, 0, stream>>>(bufA, W1, b1, bufB, N, K1);
    // layer 2
    aggregate_kernel<4><<<(N + 3) / 4, 256, 0, stream>>>(bufB, bufA, off, csr, dinv, N);
    gemm_bias_relu_kernel<<<(N + 63) / 64, 256, 0, stream>>>(bufA, W2, b2, bufB, N, 256);
    // mean-pool + classifier head
    pool_partial_kernel<<<blkN, 256, 0, stream>>>(bufB, batch, gsum, N);
    pool_final_kernel<<<G, 256, 0, stream>>>(gsum, cnt, Wc, bc, out);
}

// Round 4
// 771.079 us; speedup vs baseline: 1.9397x; 1.2870x over previous
//
#include <hip/hip_runtime.h>
#include <cstdint>
#include <cstddef>

// ---------------------------------------------------------------------------
// WindowGCN: 2-layer GCN + mean-pool + linear head.
//   h1 = relu((A_hat @ x) @ W1 + b1)      (aggregate-first)
//   h2 = relu((A_hat @ h1) @ W2 + b2)
//   out = mean_pool(h2, batch) @ Wc + bc
// R4: heavy path in bf16 -- gathers move half the bytes, GEMMs use
//     v_mfma_f32_16x16x32_bf16 (fp32 accum). h2/pool/head stay fp32.
// ---------------------------------------------------------------------------

typedef __attribute__((ext_vector_type(8))) short bf16x8;
typedef __attribute__((ext_vector_type(4))) float f32x4;

__device__ inline unsigned short f2bf(float f) {  // RNE fp32 -> bf16
    unsigned u = __float_as_uint(f);
    u = (u + 0x7FFFu + ((u >> 16) & 1u)) >> 16;
    return (unsigned short)u;
}
__device__ inline float bf_lo(unsigned v) { return __uint_as_float(v << 16); }
__device__ inline float bf_hi(unsigned v) { return __uint_as_float(v & 0xFFFF0000u); }

// ---------------- graph prep ----------------

__global__ __launch_bounds__(256) void deg_count_kernel(const int* __restrict__ dst,
                                                        int* __restrict__ deg, int E) {
    int e = blockIdx.x * 256 + threadIdx.x;
    if (e < E) atomicAdd(&deg[dst[e]], 1);
}

__global__ __launch_bounds__(256) void graph_count_kernel(const int* __restrict__ batch,
                                                          int* __restrict__ cnt, int N) {
    __shared__ int h[256];
    int t = threadIdx.x;
    h[t] = 0;
    __syncthreads();
    int n = blockIdx.x * 256 + t;
    if (n < N) atomicAdd(&h[batch[n]], 1);
    __syncthreads();
    if (h[t] != 0) atomicAdd(&cnt[t], h[t]);
}

__global__ __launch_bounds__(256) void dinv_kernel(const int* __restrict__ deg,
                                                   float* __restrict__ dinv, int N) {
    int n = blockIdx.x * 256 + threadIdx.x;
    if (n < N) dinv[n] = rsqrtf((float)deg[n] + 1.0f);
}

__global__ __launch_bounds__(1024) void scan_kernel(const int* __restrict__ deg,
                                                    int* __restrict__ off, int N) {
    __shared__ int wsum[16];
    __shared__ int carry_s;
    int t = threadIdx.x, lane = t & 63, w = t >> 6;
    if (t == 0) { carry_s = 0; off[0] = 0; }
    __syncthreads();
    for (int base = 0; base < N; base += 4096) {
        int idx = base + t * 4;
        int v0 = (idx + 0 < N) ? deg[idx + 0] : 0;
        int v1 = (idx + 1 < N) ? deg[idx + 1] : 0;
        int v2 = (idx + 2 < N) ? deg[idx + 2] : 0;
        int v3 = (idx + 3 < N) ? deg[idx + 3] : 0;
        int i0 = v0, i1 = i0 + v1, i2 = i1 + v2, i3 = i2 + v3;
        int x = i3;
        #pragma unroll
        for (int d = 1; d < 64; d <<= 1) {
            int y = __shfl_up(x, d, 64);
            if (lane >= d) x += y;
        }
        if (lane == 63) wsum[w] = x;
        __syncthreads();
        int woff = 0;
        #pragma unroll
        for (int j = 0; j < 16; j++)
            if (j < w) woff += wsum[j];
        int c = carry_s;
        __syncthreads();
        int pre = c + woff + (x - i3);
        if (idx + 0 < N) off[idx + 1] = pre + i0;
        if (idx + 1 < N) off[idx + 2] = pre + i1;
        if (idx + 2 < N) off[idx + 3] = pre + i2;
        if (idx + 3 < N) off[idx + 4] = pre + i3;
        if (t == 1023) carry_s = pre + i3;
        __syncthreads();
    }
}

__global__ __launch_bounds__(256) void csr_fill_kernel(const int* __restrict__ src,
                                                       const int* __restrict__ dst,
                                                       const int* __restrict__ off,
                                                       int* __restrict__ cursor,
                                                       int* __restrict__ csr, int E) {
    int e = blockIdx.x * 256 + threadIdx.x;
    if (e < E) {
        int d = dst[e];
        int p = off[d] + atomicAdd(&cursor[d], 1);
        csr[p] = src[e];
    }
}

// ---------------- dtype prep ----------------

__global__ __launch_bounds__(256) void f32_to_bf16_kernel(const float* __restrict__ in,
                                                          unsigned short* __restrict__ out,
                                                          long n4) {  // n4 = n/4
    long i = (long)blockIdx.x * 256 + threadIdx.x;
    if (i < n4) {
        float4 v = reinterpret_cast<const float4*>(in)[i];
        ushort4 o;
        o.x = f2bf(v.x); o.y = f2bf(v.y); o.z = f2bf(v.z); o.w = f2bf(v.w);
        reinterpret_cast<ushort4*>(out)[i] = o;
    }
}

// W [K][256] fp32 -> WT [256][K] bf16
__global__ __launch_bounds__(256) void transpose_w_kernel(const float* __restrict__ W,
                                                          unsigned short* __restrict__ WT,
                                                          int K) {
    int idx = blockIdx.x * 256 + threadIdx.x;
    if (idx < K * 256) {
        int k = idx >> 8, n = idx & 255;
        WT[n * K + k] = f2bf(W[idx]);
    }
}

// ---------------- aggregation (bf16 in/out, fp32 accum) ----------------
// OUT[i] = dinv[i] * ( dinv[i]*X[i] + sum_{s in in(i)} dinv[s]*X[s] )
// One wave per node; lane owns VEC bf16 columns (F = VEC*64).
template <int VEC>
__global__ __launch_bounds__(256) void aggregate_bf16_kernel(
        const unsigned short* __restrict__ X, unsigned short* __restrict__ OUT,
        const int* __restrict__ off, const int* __restrict__ csr,
        const float* __restrict__ dinv, int N) {
    constexpr int F = VEC * 64;
    int w = threadIdx.x >> 6, lane = threadIdx.x & 63;
    int node = blockIdx.x * 4 + w;
    if (node >= N) return;
    float di = dinv[node];
    float acc[VEC];
    if constexpr (VEC == 4) {
        uint2 v = *reinterpret_cast<const uint2*>(X + (size_t)node * F + lane * 4);
        acc[0] = di * bf_lo(v.x); acc[1] = di * bf_hi(v.x);
        acc[2] = di * bf_lo(v.y); acc[3] = di * bf_hi(v.y);
    } else {
        unsigned v = *reinterpret_cast<const unsigned*>(X + (size_t)node * F + lane * 2);
        acc[0] = di * bf_lo(v); acc[1] = di * bf_hi(v);
    }
    int e0 = off[node], e1 = off[node + 1];
    for (int e = e0; e < e1; e++) {
        int s = csr[e];
        float ds = dinv[s];
        if constexpr (VEC == 4) {
            uint2 v = *reinterpret_cast<const uint2*>(X + (size_t)s * F + lane * 4);
            acc[0] += ds * bf_lo(v.x); acc[1] += ds * bf_hi(v.x);
            acc[2] += ds * bf_lo(v.y); acc[3] += ds * bf_hi(v.y);
        } else {
            unsigned v = *reinterpret_cast<const unsigned*>(X + (size_t)s * F + lane * 2);
            acc[0] += ds * bf_lo(v); acc[1] += ds * bf_hi(v);
        }
    }
    if constexpr (VEC == 4) {
        uint2 o;
        o.x = (unsigned)f2bf(di * acc[0]) | ((unsigned)f2bf(di * acc[1]) << 16);
        o.y = (unsigned)f2bf(di * acc[2]) | ((unsigned)f2bf(di * acc[3]) << 16);
        *reinterpret_cast<uint2*>(OUT + (size_t)node * F + lane * 4) = o;
    } else {
        unsigned o = (unsigned)f2bf(di * acc[0]) | ((unsigned)f2bf(di * acc[1]) << 16);
        *reinterpret_cast<unsigned*>(OUT + (size_t)node * F + lane * 2) = o;
    }
}

// ---------------- MFMA GEMM ----------------
// C[M][256] = relu(A[M][K]@W + bias), A bf16 row-major, WT = W^T bf16 [256][K].
// Block: 256 thr / 4 waves, tile 64x256; wave w owns cols [w*64, w*64+64):
// 4x4 fragments of 16x16. A staged to LDS via global_load_lds with
// pre-swizzled source (XOR (row&7)<<4) so ds_read_b128 is conflict-free.
template <int K, bool OUT_BF16>
__global__ __launch_bounds__(256) void mfma_gemm_kernel(
        const unsigned short* __restrict__ A, const unsigned short* __restrict__ WT,
        const float* __restrict__ bias, void* __restrict__ C, int M) {
    __shared__ unsigned short As[64 * 64];  // 64 rows x 64 bf16 (128B/row), 8KB
    const int t = threadIdx.x;
    const int lane = t & 63, w = t >> 6;
    const int r0 = blockIdx.x * 64;
    const int lhi = lane >> 4, l15 = lane & 15;

    f32x4 acc[4][4];
    #pragma unroll
    for (int i = 0; i < 4; i++)
        #pragma unroll
        for (int j = 0; j < 4; j++) acc[i][j] = (f32x4){0.f, 0.f, 0.f, 0.f};

    for (int k0 = 0; k0 < K; k0 += 64) {
        #pragma unroll
        for (int p = 0; p < 2; p++) {
            int idx = p * 256 + t;           // 512 x 16B chunks
            int row = idx >> 3;              // 8 chunks per 128B row
            int sbyte = ((idx & 7) * 16) ^ ((row & 7) << 4);  // inverse swizzle on src
            const char* g = (const char*)(A + (size_t)(r0 + row) * K + k0) + sbyte;
            __builtin_amdgcn_global_load_lds(
                (const __attribute__((address_space(1))) void*)g,
                (__attribute__((address_space(3))) void*)((char*)As + idx * 16),
                16, 0, 0);
        }
        __syncthreads();
        #pragma unroll
        for (int kk = 0; kk < 64; kk += 32) {
            bf16x8 a[4], b[4];
            #pragma unroll
            for (int mf = 0; mf < 4; mf++) {
                int row = mf * 16 + l15;
                int kb = (kk + lhi * 8) * 2;
                a[mf] = *reinterpret_cast<const bf16x8*>(
                    (const char*)As + row * 128 + (kb ^ ((row & 7) << 4)));
            }
            #pragma unroll
            for (int nf = 0; nf < 4; nf++) {
                int n = w * 64 + nf * 16 + l15;
                b[nf] = *reinterpret_cast<const bf16x8*>(WT + (size_t)n * K + k0 + kk + lhi * 8);
            }
            #pragma unroll
            for (int mf = 0; mf < 4; mf++)
                #pragma unroll
                for (int nf = 0; nf < 4; nf++)
                    acc[mf][nf] = __builtin_amdgcn_mfma_f32_16x16x32_bf16(
                        a[mf], b[nf], acc[mf][nf], 0, 0, 0);
        }
        __syncthreads();
    }
    #pragma unroll
    for (int nf = 0; nf < 4; nf++) {
        int n = w * 64 + nf * 16 + l15;
        float bn = bias[n];
        #pragma unroll
        for (int mf = 0; mf < 4; mf++) {
            #pragma unroll
            for (int j = 0; j < 4; j++) {
                int m = r0 + mf * 16 + lhi * 4 + j;
                if (m < M) {
                    float v = fmaxf(acc[mf][nf][j] + bn, 0.f);
                    if constexpr (OUT_BF16)
                        ((unsigned short*)C)[(size_t)m * 256 + n] = f2bf(v);
                    else
                        ((float*)C)[(size_t)m * 256 + n] = v;
                }
            }
        }
    }
}

// ---------------- pooling + head (fp32) ----------------

__global__ __launch_bounds__(256) void pool_partial_kernel(const float* __restrict__ H,
                                                           const int* __restrict__ batch,
                                                           float* __restrict__ gsum, int N) {
    int t = threadIdx.x;
    int n0 = blockIdx.x * 256;
    int nend = min(n0 + 256, N);
    int cur = batch[n0];
    float acc = 0.f;
    for (int n = n0; n < nend; n++) {
        int b = batch[n];
        if (b != cur) {
            atomicAdd(&gsum[cur * 256 + t], acc);
            acc = 0.f;
            cur = b;
        }
        acc += H[(size_t)n * 256 + t];
    }
    atomicAdd(&gsum[cur * 256 + t], acc);
}

__global__ __launch_bounds__(256) void pool_final_kernel(const float* __restrict__ gsum,
                                                         const int* __restrict__ cnt,
                                                         const float* __restrict__ Wc,
                                                         const float* __restrict__ bc,
                                                         float* __restrict__ out) {
    __shared__ float gm[256];
    int g = blockIdx.x, t = threadIdx.x;
    float inv = 1.0f / fmaxf((float)cnt[g], 1.0f);
    gm[t] = gsum[g * 256 + t] * inv;
    __syncthreads();
    if (t < 200) {
        float acc = bc[t];
        #pragma unroll 8
        for (int k = 0; k < 256; k++) acc += gm[k] * Wc[k * 200 + t];
        out[g * 200 + t] = acc;
    }
}

// ---------------- driver ----------------

extern "C" void kernel_launch(void* const* d_in, const int* in_sizes, int n_in,
                              void* d_out, int out_size, void* d_ws, size_t ws_size,
                              hipStream_t stream) {
    const float* x   = (const float*)d_in[0];
    const int* ei    = (const int*)d_in[1];
    const int* batch = (const int*)d_in[2];
    const float* W1  = (const float*)d_in[4];
    const float* b1  = (const float*)d_in[5];
    const float* W2  = (const float*)d_in[6];
    const float* b2  = (const float*)d_in[7];
    const float* Wc  = (const float*)d_in[8];
    const float* bc  = (const float*)d_in[9];
    float* out = (float*)d_out;

    const int N = in_sizes[2];       // 100000
    const int E = in_sizes[1] / 2;   // 1600000
    const int G = out_size / 200;    // 64
    const int K1 = in_sizes[0] / N;  // 128
    const int Mpad = (N + 63) & ~63; // 100032
    const int* src = ei;
    const int* dst = ei + E;

    char* p = (char*)d_ws;
    auto alloc = [&](size_t bytes) -> char* {
        char* r = p;
        p += (bytes + 255) & ~(size_t)255;
        return r;
    };
    int*   off    = (int*)alloc((size_t)(N + 1) * 4);
    int*   deg    = (int*)alloc((size_t)N * 4);
    int*   cursor = (int*)alloc((size_t)N * 4);
    int*   cnt    = (int*)alloc(256 * 4);
    float* dinv   = (float*)alloc((size_t)N * 4);
    float* gsum   = (float*)alloc((size_t)G * 256 * 4);
    int*   csr    = (int*)alloc((size_t)E * 4);
    unsigned short* WT1 = (unsigned short*)alloc((size_t)256 * K1 * 2);
    unsigned short* WT2 = (unsigned short*)alloc((size_t)256 * 256 * 2);
    // lifetime-shared big slots (each Mpad*256*2 = 51.2 MB)
    size_t slot = (size_t)Mpad * 256 * 2;
    char* slotB = alloc(slot);        // a1 (first half) -> a2
    char* slotA = alloc(slot);        // xh (first half) -> h1 -> h2 (with slotC)
    char* slotC = alloc(slot);        // h2 upper half (slotA+slotC contiguous)
    (void)slotC;
    unsigned short* xh = (unsigned short*)slotA;  // [Mpad][128]
    unsigned short* a1 = (unsigned short*)slotB;  // [Mpad][128]
    unsigned short* h1 = (unsigned short*)slotA;  // [Mpad][256]
    unsigned short* a2 = (unsigned short*)slotB;  // [Mpad][256]
    float*          h2 = (float*)slotA;           // [Mpad][256] fp32 (slotA+slotC)

    hipMemsetAsync(deg, 0, (size_t)N * 4, stream);
    hipMemsetAsync(cursor, 0, (size_t)N * 4, stream);
    hipMemsetAsync(cnt, 0, 256 * 4, stream);
    hipMemsetAsync(gsum, 0, (size_t)G * 256 * 4, stream);

    int blkE = (E + 255) / 256, blkN = (N + 255) / 256;
    deg_count_kernel<<<blkE, 256, 0, stream>>>(dst, deg, E);
    graph_count_kernel<<<blkN, 256, 0, stream>>>(batch, cnt, N);
    dinv_kernel<<<blkN, 256, 0, stream>>>(deg, dinv, N);
    scan_kernel<<<1, 1024, 0, stream>>>(deg, off, N);
    csr_fill_kernel<<<blkE, 256, 0, stream>>>(src, dst, off, cursor, csr, E);

    long n4 = (long)N * K1 / 4;
    f32_to_bf16_kernel<<<(int)((n4 + 255) / 256), 256, 0, stream>>>(x, xh, n4);
    transpose_w_kernel<<<(K1 * 256 + 255) / 256, 256, 0, stream>>>(W1, WT1, K1);
    transpose_w_kernel<<<(256 * 256 + 255) / 256, 256, 0, stream>>>(W2, WT2, 256);

    int gemm_blocks = Mpad / 64;  // 1563
    // layer 1
    aggregate_bf16_kernel<2><<<(N + 3) / 4, 256, 0, stream>>>(xh, a1, off, csr, dinv, N);
    mfma_gemm_kernel<128, true><<<gemm_blocks, 256, 0, stream>>>(a1, WT1, b1, h1, N);
    // layer 2
    aggregate_bf16_kernel<4><<<(N + 3) / 4, 256, 0, stream>>>(h1, a2, off, csr, dinv, N);
    mfma_gemm_kernel<256, false><<<gemm_blocks, 256, 0, stream>>>(a2, WT2, b2, h2, N);
    // pool + head
    pool_partial_kernel<<<blkN, 256, 0, stream>>>(h2, batch, gsum, N);
    pool_final_kernel<<<G, 256, 0, stream>>>(gsum, cnt, Wc, bc, out);
}

// Round 5
// 584.578 us; speedup vs baseline: 2.5585x; 1.3190x over previous
//
#include <hip/hip_runtime.h>
#include <cstdint>
#include <cstddef>

// ---------------------------------------------------------------------------
// WindowGCN: 2-layer GCN + mean-pool + linear head.
// R5: prescaled-Y formulation  out[i] = dinv[i]*(Y[i] + sum_in Y[s]),
//     Y = dinv (.) h  -- folded into conversion / GEMM1 epilogue. Gather loop
//     is scalarized (readfirstlane node) + 8x unrolled for MLP. GEMM stages
//     both A and W^T in LDS via pre-swizzled global_load_lds; h2 in bf16.
// ---------------------------------------------------------------------------

typedef __attribute__((ext_vector_type(8))) short bf16x8;
typedef __attribute__((ext_vector_type(4))) float f32x4;

__device__ inline unsigned short f2bf(float f) {  // RNE fp32 -> bf16
    unsigned u = __float_as_uint(f);
    u = (u + 0x7FFFu + ((u >> 16) & 1u)) >> 16;
    return (unsigned short)u;
}
__device__ inline float bf_lo(unsigned v) { return __uint_as_float(v << 16); }
__device__ inline float bf_hi(unsigned v) { return __uint_as_float(v & 0xFFFF0000u); }

// ---------------- graph prep ----------------

__global__ __launch_bounds__(256) void deg_count_kernel(const int* __restrict__ dst,
                                                        int* __restrict__ deg, int E) {
    int e = blockIdx.x * 256 + threadIdx.x;
    if (e < E) atomicAdd(&deg[dst[e]], 1);
}

__global__ __launch_bounds__(256) void graph_count_kernel(const int* __restrict__ batch,
                                                          int* __restrict__ cnt, int N) {
    __shared__ int h[256];
    int t = threadIdx.x;
    h[t] = 0;
    __syncthreads();
    int n = blockIdx.x * 256 + t;
    if (n < N) atomicAdd(&h[batch[n]], 1);
    __syncthreads();
    if (h[t] != 0) atomicAdd(&cnt[t], h[t]);
}

__global__ __launch_bounds__(256) void dinv_kernel(const int* __restrict__ deg,
                                                   float* __restrict__ dinv, int N) {
    int n = blockIdx.x * 256 + threadIdx.x;
    if (n < N) dinv[n] = rsqrtf((float)deg[n] + 1.0f);
}

__global__ __launch_bounds__(1024) void scan_kernel(const int* __restrict__ deg,
                                                    int* __restrict__ off, int N) {
    __shared__ int wsum[16];
    __shared__ int carry_s;
    int t = threadIdx.x, lane = t & 63, w = t >> 6;
    if (t == 0) { carry_s = 0; off[0] = 0; }
    __syncthreads();
    for (int base = 0; base < N; base += 4096) {
        int idx = base + t * 4;
        int v0 = (idx + 0 < N) ? deg[idx + 0] : 0;
        int v1 = (idx + 1 < N) ? deg[idx + 1] : 0;
        int v2 = (idx + 2 < N) ? deg[idx + 2] : 0;
        int v3 = (idx + 3 < N) ? deg[idx + 3] : 0;
        int i0 = v0, i1 = i0 + v1, i2 = i1 + v2, i3 = i2 + v3;
        int x = i3;
        #pragma unroll
        for (int d = 1; d < 64; d <<= 1) {
            int y = __shfl_up(x, d, 64);
            if (lane >= d) x += y;
        }
        if (lane == 63) wsum[w] = x;
        __syncthreads();
        int woff = 0;
        #pragma unroll
        for (int j = 0; j < 16; j++)
            if (j < w) woff += wsum[j];
        int c = carry_s;
        __syncthreads();
        int pre = c + woff + (x - i3);
        if (idx + 0 < N) off[idx + 1] = pre + i0;
        if (idx + 1 < N) off[idx + 2] = pre + i1;
        if (idx + 2 < N) off[idx + 3] = pre + i2;
        if (idx + 3 < N) off[idx + 4] = pre + i3;
        if (t == 1023) carry_s = pre + i3;
        __syncthreads();
    }
}

__global__ __launch_bounds__(256) void csr_fill_kernel(const int* __restrict__ src,
                                                       const int* __restrict__ dst,
                                                       const int* __restrict__ off,
                                                       int* __restrict__ cursor,
                                                       int* __restrict__ csr, int E) {
    int e = blockIdx.x * 256 + threadIdx.x;
    if (e < E) {
        int d = dst[e];
        int p = off[d] + atomicAdd(&cursor[d], 1);
        csr[p] = src[e];
    }
}

// ---------------- dtype prep: Y0 = dinv (.) x, bf16 ----------------
// thread i handles 4 consecutive floats; row = i >> shift (shift = log2(D/4))
__global__ __launch_bounds__(256) void prescale_bf16_kernel(const float* __restrict__ in,
                                                            const float* __restrict__ dinv,
                                                            unsigned short* __restrict__ out,
                                                            long n4, int shift) {
    long i = (long)blockIdx.x * 256 + threadIdx.x;
    if (i < n4) {
        float d = dinv[i >> shift];
        float4 v = reinterpret_cast<const float4*>(in)[i];
        ushort4 o;
        o.x = f2bf(d * v.x); o.y = f2bf(d * v.y);
        o.z = f2bf(d * v.z); o.w = f2bf(d * v.w);
        reinterpret_cast<ushort4*>(out)[i] = o;
    }
}

// W [K][256] fp32 -> WT [256][K] bf16
__global__ __launch_bounds__(256) void transpose_w_kernel(const float* __restrict__ W,
                                                          unsigned short* __restrict__ WT,
                                                          int K) {
    int idx = blockIdx.x * 256 + threadIdx.x;
    if (idx < K * 256) {
        int k = idx >> 8, n = idx & 255;
        WT[n * K + k] = f2bf(W[idx]);
    }
}

// ---------------- aggregation: OUT[i] = di * (Y[i] + sum_in Y[s]) ----------
// One wave per node (scalarized); lane owns VEC bf16 cols; 8x-unrolled gather.
template <int VEC>  // 2 or 4; F = VEC*64; row stride = 64 dwords either way
__global__ __launch_bounds__(256) void aggregate_kernel(
        const unsigned short* __restrict__ Y, unsigned short* __restrict__ OUT,
        const int* __restrict__ off, const int* __restrict__ csr,
        const float* __restrict__ dinv, int N) {
    constexpr int F = VEC * 64;
    int node = __builtin_amdgcn_readfirstlane(blockIdx.x * 4 + (threadIdx.x >> 6));
    int lane = threadIdx.x & 63;
    if (node >= N) return;

    float acc[VEC];
    auto loadrow = [&](int s) -> uint2 {
        if constexpr (VEC == 4)
            return reinterpret_cast<const uint2*>(Y)[(size_t)s * 64 + lane];
        else
            return make_uint2(reinterpret_cast<const unsigned*>(Y)[(size_t)s * 64 + lane], 0u);
    };
    auto addrow = [&](uint2 v) {
        acc[0] += bf_lo(v.x);
        acc[1] += bf_hi(v.x);
        if constexpr (VEC == 4) {
            acc[2] += bf_lo(v.y);
            acc[3] += bf_hi(v.y);
        }
    };
    // self row (Y already dinv-scaled; self-loop folds in)
    {
        uint2 v = loadrow(node);
        acc[0] = bf_lo(v.x);
        acc[1] = bf_hi(v.x);
        if constexpr (VEC == 4) { acc[2] = bf_lo(v.y); acc[3] = bf_hi(v.y); }
    }
    int e0 = off[node], e1 = off[node + 1];
    int e = e0;
    for (; e + 8 <= e1; e += 8) {
        int s0 = csr[e + 0], s1 = csr[e + 1], s2 = csr[e + 2], s3 = csr[e + 3];
        int s4 = csr[e + 4], s5 = csr[e + 5], s6 = csr[e + 6], s7 = csr[e + 7];
        uint2 v0 = loadrow(s0), v1 = loadrow(s1), v2 = loadrow(s2), v3 = loadrow(s3);
        uint2 v4 = loadrow(s4), v5 = loadrow(s5), v6 = loadrow(s6), v7 = loadrow(s7);
        addrow(v0); addrow(v1); addrow(v2); addrow(v3);
        addrow(v4); addrow(v5); addrow(v6); addrow(v7);
    }
    for (; e < e1; e++) addrow(loadrow(csr[e]));

    float di = dinv[node];
    if constexpr (VEC == 4) {
        uint2 o;
        o.x = (unsigned)f2bf(di * acc[0]) | ((unsigned)f2bf(di * acc[1]) << 16);
        o.y = (unsigned)f2bf(di * acc[2]) | ((unsigned)f2bf(di * acc[3]) << 16);
        reinterpret_cast<uint2*>(OUT)[(size_t)node * 64 + lane] = o;
    } else {
        unsigned o = (unsigned)f2bf(di * acc[0]) | ((unsigned)f2bf(di * acc[1]) << 16);
        reinterpret_cast<unsigned*>(OUT)[(size_t)node * 64 + lane] = o;
    }
}

// ---------------- MFMA GEMM ----------------
// C[M][256] = post(relu(A[M][K]@W + bias)), A bf16 row-major, WT=W^T bf16.
// 256 thr / 4 waves, tile 64x256. A (8KB) + W^T k-chunk (32KB) staged in LDS
// via global_load_lds with pre-swizzled source; XOR (r&7)<<4 kills the
// stride-128B bank conflict on ds_read_b128.
// SCALE_DINV: C[m] *= dinv[m] (produces Y for the next gather). Output bf16.
template <int K, bool SCALE_DINV>
__global__ __launch_bounds__(256) void mfma_gemm_kernel(
        const unsigned short* __restrict__ A, const unsigned short* __restrict__ WT,
        const float* __restrict__ bias, const float* __restrict__ dinv,
        unsigned short* __restrict__ C, int M) {
    __shared__ unsigned short As[64 * 64];    // 64 rows x 64 k, 128B rows, 8KB
    __shared__ unsigned short Ws[256 * 64];   // 256 cols x 64 k, 128B rows, 32KB
    const int t = threadIdx.x;
    const int lane = t & 63, w = t >> 6;
    const int r0 = blockIdx.x * 64;
    const int lhi = lane >> 4, l15 = lane & 15;

    f32x4 acc[4][4];
    #pragma unroll
    for (int i = 0; i < 4; i++)
        #pragma unroll
        for (int j = 0; j < 4; j++) acc[i][j] = (f32x4){0.f, 0.f, 0.f, 0.f};

    for (int k0 = 0; k0 < K; k0 += 64) {
        #pragma unroll
        for (int p = 0; p < 2; p++) {  // A: 512 x 16B chunks
            int idx = p * 256 + t;
            int row = idx >> 3;
            int sbyte = ((idx & 7) * 16) ^ ((row & 7) << 4);
            const char* g = (const char*)(A + (size_t)(r0 + row) * K + k0) + sbyte;
            __builtin_amdgcn_global_load_lds(
                (const __attribute__((address_space(1))) void*)g,
                (__attribute__((address_space(3))) void*)((char*)As + idx * 16),
                16, 0, 0);
        }
        #pragma unroll
        for (int q = 0; q < 8; q++) {  // W^T chunk: 2048 x 16B chunks
            int idx = q * 256 + t;
            int col = idx >> 3;
            int sbyte = ((idx & 7) * 16) ^ ((col & 7) << 4);
            const char* g = (const char*)(WT + (size_t)col * K + k0) + sbyte;
            __builtin_amdgcn_global_load_lds(
                (const __attribute__((address_space(1))) void*)g,
                (__attribute__((address_space(3))) void*)((char*)Ws + idx * 16),
                16, 0, 0);
        }
        __syncthreads();
        #pragma unroll
        for (int kk = 0; kk < 64; kk += 32) {
            bf16x8 a[4], b[4];
            int kb = (kk + lhi * 8) * 2;
            #pragma unroll
            for (int mf = 0; mf < 4; mf++) {
                int row = mf * 16 + l15;
                a[mf] = *reinterpret_cast<const bf16x8*>(
                    (const char*)As + row * 128 + (kb ^ ((row & 7) << 4)));
            }
            #pragma unroll
            for (int nf = 0; nf < 4; nf++) {
                int col = w * 64 + nf * 16 + l15;
                b[nf] = *reinterpret_cast<const bf16x8*>(
                    (const char*)Ws + col * 128 + (kb ^ ((col & 7) << 4)));
            }
            #pragma unroll
            for (int mf = 0; mf < 4; mf++)
                #pragma unroll
                for (int nf = 0; nf < 4; nf++)
                    acc[mf][nf] = __builtin_amdgcn_mfma_f32_16x16x32_bf16(
                        a[mf], b[nf], acc[mf][nf], 0, 0, 0);
        }
        __syncthreads();
    }
    #pragma unroll
    for (int mf = 0; mf < 4; mf++) {
        #pragma unroll
        for (int j = 0; j < 4; j++) {
            int m = r0 + mf * 16 + lhi * 4 + j;
            if (m < M) {
                float s = SCALE_DINV ? dinv[m] : 1.0f;
                #pragma unroll
                for (int nf = 0; nf < 4; nf++) {
                    int n = w * 64 + nf * 16 + l15;
                    float v = fmaxf(acc[mf][nf][j] + bias[n], 0.f) * s;
                    C[(size_t)m * 256 + n] = f2bf(v);
                }
            }
        }
    }
}

// ---------------- pooling + head ----------------

__global__ __launch_bounds__(256) void pool_partial_kernel(const unsigned short* __restrict__ H,
                                                           const int* __restrict__ batch,
                                                           float* __restrict__ gsum, int N) {
    int t = threadIdx.x;
    int n0 = blockIdx.x * 256;
    int nend = min(n0 + 256, N);
    int cur = batch[n0];
    float acc = 0.f;
    for (int n = n0; n < nend; n++) {
        int b = batch[n];
        if (b != cur) {
            atomicAdd(&gsum[cur * 256 + t], acc);
            acc = 0.f;
            cur = b;
        }
        acc += __uint_as_float((unsigned)H[(size_t)n * 256 + t] << 16);
    }
    atomicAdd(&gsum[cur * 256 + t], acc);
}

__global__ __launch_bounds__(256) void pool_final_kernel(const float* __restrict__ gsum,
                                                         const int* __restrict__ cnt,
                                                         const float* __restrict__ Wc,
                                                         const float* __restrict__ bc,
                                                         float* __restrict__ out) {
    __shared__ float gm[256];
    int g = blockIdx.x, t = threadIdx.x;
    float inv = 1.0f / fmaxf((float)cnt[g], 1.0f);
    gm[t] = gsum[g * 256 + t] * inv;
    __syncthreads();
    if (t < 200) {
        float acc = bc[t];
        #pragma unroll 8
        for (int k = 0; k < 256; k++) acc += gm[k] * Wc[k * 200 + t];
        out[g * 200 + t] = acc;
    }
}

// ---------------- driver ----------------

extern "C" void kernel_launch(void* const* d_in, const int* in_sizes, int n_in,
                              void* d_out, int out_size, void* d_ws, size_t ws_size,
                              hipStream_t stream) {
    const float* x   = (const float*)d_in[0];
    const int* ei    = (const int*)d_in[1];
    const int* batch = (const int*)d_in[2];
    const float* W1  = (const float*)d_in[4];
    const float* b1  = (const float*)d_in[5];
    const float* W2  = (const float*)d_in[6];
    const float* b2  = (const float*)d_in[7];
    const float* Wc  = (const float*)d_in[8];
    const float* bc  = (const float*)d_in[9];
    float* out = (float*)d_out;

    const int N = in_sizes[2];       // 100000
    const int E = in_sizes[1] / 2;   // 1600000
    const int G = out_size / 200;    // 64
    const int K1 = in_sizes[0] / N;  // 128
    const int Mpad = (N + 63) & ~63; // 100032
    const int* src = ei;
    const int* dst = ei + E;

    char* p = (char*)d_ws;
    auto alloc = [&](size_t bytes) -> char* {
        char* r = p;
        p += (bytes + 255) & ~(size_t)255;
        return r;
    };
    int*   off    = (int*)alloc((size_t)(N + 1) * 4);
    int*   deg    = (int*)alloc((size_t)N * 4);
    int*   cursor = (int*)alloc((size_t)N * 4);
    int*   cnt    = (int*)alloc(256 * 4);
    float* dinv   = (float*)alloc((size_t)N * 4);
    float* gsum   = (float*)alloc((size_t)G * 256 * 4);
    int*   csr    = (int*)alloc((size_t)E * 4);
    unsigned short* WT1 = (unsigned short*)alloc((size_t)256 * K1 * 2);
    unsigned short* WT2 = (unsigned short*)alloc((size_t)256 * 256 * 2);
    size_t slot = (size_t)Mpad * 256 * 2;   // 51.2 MB
    unsigned short* slotA = (unsigned short*)alloc(slot);  // Y0 -> Y1 -> h2
    unsigned short* slotB = (unsigned short*)alloc(slot);  // a1 -> a2
    unsigned short* Y0 = slotA;  // [N][128]
    unsigned short* a1 = slotB;  // [N][128]
    unsigned short* Y1 = slotA;  // [Mpad][256]
    unsigned short* a2 = slotB;  // [N][256]
    unsigned short* h2 = slotA;  // [Mpad][256]

    hipMemsetAsync(deg, 0, (size_t)N * 4, stream);
    hipMemsetAsync(cursor, 0, (size_t)N * 4, stream);
    hipMemsetAsync(cnt, 0, 256 * 4, stream);
    hipMemsetAsync(gsum, 0, (size_t)G * 256 * 4, stream);

    int blkE = (E + 255) / 256, blkN = (N + 255) / 256;
    deg_count_kernel<<<blkE, 256, 0, stream>>>(dst, deg, E);
    graph_count_kernel<<<blkN, 256, 0, stream>>>(batch, cnt, N);
    dinv_kernel<<<blkN, 256, 0, stream>>>(deg, dinv, N);

    long n4 = (long)N * K1 / 4;
    int shift = 31 - __builtin_clz(K1 / 4);  // K1=128 -> 5
    prescale_bf16_kernel<<<(int)((n4 + 255) / 256), 256, 0, stream>>>(x, dinv, Y0, n4, shift);
    transpose_w_kernel<<<(K1 * 256 + 255) / 256, 256, 0, stream>>>(W1, WT1, K1);
    transpose_w_kernel<<<(256 * 256 + 255) / 256, 256, 0, stream>>>(W2, WT2, 256);

    scan_kernel<<<1, 1024, 0, stream>>>(deg, off, N);
    csr_fill_kernel<<<blkE, 256, 0, stream>>>(src, dst, off, cursor, csr, E);

    int gemm_blocks = Mpad / 64;
    // layer 1
    aggregate_kernel<2><<<(N + 3) / 4, 256, 0, stream>>>(Y0, a1, off, csr, dinv, N);
    mfma_gemm_kernel<128, true><<<gemm_blocks, 256, 0, stream>>>(a1, WT1, b1, dinv, Y1, N);
    // layer 2
    aggregate_kernel<4><<<(N + 3) / 4, 256, 0, stream>>>(Y1, a2, off, csr, dinv, N);
    mfma_gemm_kernel<256, false><<<gemm_blocks, 256, 0, stream>>>(a2, WT2, b2, nullptr, h2, N);
    // pool + head
    pool_partial_kernel<<<blkN, 256, 0, stream>>>(h2, batch, gsum, N);
    pool_final_kernel<<<G, 256, 0, stream>>>(gsum, cnt, Wc, bc, out);
}

// Round 6
// 395.794 us; speedup vs baseline: 3.7788x; 1.4770x over previous
//
#include <hip/hip_runtime.h>
#include <cstdint>
#include <cstddef>

// ---------------------------------------------------------------------------
// WindowGCN: 2-layer GCN + mean-pool + linear head.
// R6: CSR build via 2-level bucket sort (coarse 256-node buckets, then
//     per-bucket LDS counting sort). Kills csr_fill's 16x write amplification
//     (107MB -> ~8MB HBM writes) and absorbs deg_count/dinv/scan. Aggregate
//     gather unrolled 16x. Heavy path bf16 (prescaled-Y formulation):
//     out[i] = dinv[i]*(Y[i] + sum_in Y[s]), Y = dinv (.) h.
// ---------------------------------------------------------------------------

typedef __attribute__((ext_vector_type(8))) short bf16x8;
typedef __attribute__((ext_vector_type(4))) float f32x4;

#define P1_CHUNK 4096
#define BCAP 8192  // pairs capacity per 256-node bucket (mean 4093, +64 sigma)

__device__ inline unsigned short f2bf(float f) {  // RNE fp32 -> bf16
    unsigned u = __float_as_uint(f);
    u = (u + 0x7FFFu + ((u >> 16) & 1u)) >> 16;
    return (unsigned short)u;
}
__device__ inline float bf_lo(unsigned v) { return __uint_as_float(v << 16); }
__device__ inline float bf_hi(unsigned v) { return __uint_as_float(v & 0xFFFF0000u); }

// ---------------- CSR build: pass 1 (coarse bucket scatter) ----------------
// Block handles P1_CHUNK edges: LDS histogram by bucket (dst>>8), one global
// atomic reserve per (block,bucket), then packed (src, dst&255) pair writes.
__global__ __launch_bounds__(256) void bucket_scatter_kernel(
        const int* __restrict__ src, const int* __restrict__ dst,
        int* __restrict__ bucketCnt, unsigned long long* __restrict__ pairs,
        int E, int NB) {
    __shared__ int hist[512];
    __shared__ int base[512];
    int t = threadIdx.x;
    int e0 = blockIdx.x * P1_CHUNK;
    int eend = min(e0 + P1_CHUNK, E);
    for (int i = t; i < NB; i += 256) hist[i] = 0;
    __syncthreads();
    for (int e = e0 + t; e < eend; e += 256) atomicAdd(&hist[dst[e] >> 8], 1);
    __syncthreads();
    for (int i = t; i < NB; i += 256) {
        int c = hist[i];
        base[i] = (c > 0) ? atomicAdd(&bucketCnt[i], c) : 0;
        hist[i] = 0;  // reuse as cursor
    }
    __syncthreads();
    for (int e = e0 + t; e < eend; e += 256) {
        int d = dst[e], s = src[e];
        int b = d >> 8;
        int r = base[b] + atomicAdd(&hist[b], 1);
        if (r < BCAP)
            pairs[(size_t)b * BCAP + r] =
                (unsigned long long)(unsigned)s | ((unsigned long long)(d & 255) << 32);
    }
}

// 391-entry exclusive scan of bucket counts (one block), + off[N] sentinel.
__global__ __launch_bounds__(512) void bucket_scan_kernel(
        const int* __restrict__ cnt, int* __restrict__ bbase,
        int* __restrict__ off, int NB, int N, int E) {
    __shared__ int wsum[8];
    int t = threadIdx.x, lane = t & 63, w = t >> 6;
    int v = (t < NB) ? cnt[t] : 0;
    int x = v;
    #pragma unroll
    for (int d = 1; d < 64; d <<= 1) {
        int y = __shfl_up(x, d, 64);
        if (lane >= d) x += y;
    }
    if (lane == 63) wsum[w] = x;
    __syncthreads();
    int woff = 0;
    #pragma unroll
    for (int j = 0; j < 8; j++)
        if (j < w) woff += wsum[j];
    if (t < NB) bbase[t] = woff + x - v;
    if (t == 0) off[N] = E;
}

// ---------------- CSR build: pass 2 (per-bucket counting sort) -------------
// One block per bucket: LDS histogram over 256 local nodes -> off[], dinv[];
// then LDS-cursor placement of csr into a contiguous region (L2-assembled).
__global__ __launch_bounds__(256) void fine_place_kernel(
        const unsigned long long* __restrict__ pairs, const int* __restrict__ bucketCnt,
        const int* __restrict__ bucketBase, int* __restrict__ off,
        float* __restrict__ dinv, int* __restrict__ csr, int N) {
    __shared__ int hist[256];
    __shared__ int loff[256];
    __shared__ int ws[4];
    int b = blockIdx.x, t = threadIdx.x;
    int cnt = min(bucketCnt[b], BCAP), base = bucketBase[b];
    const unsigned long long* pp = pairs + (size_t)b * BCAP;
    hist[t] = 0;
    __syncthreads();
    for (int i = t; i < cnt; i += 256) atomicAdd(&hist[(int)(pp[i] >> 32)], 1);
    __syncthreads();
    int v = hist[t];
    {   // exclusive scan of 256 bins
        int lane = t & 63, w = t >> 6;
        int x = v;
        #pragma unroll
        for (int d = 1; d < 64; d <<= 1) {
            int y = __shfl_up(x, d, 64);
            if (lane >= d) x += y;
        }
        if (lane == 63) ws[w] = x;
        __syncthreads();
        int woff = 0;
        #pragma unroll
        for (int j = 0; j < 4; j++)
            if (j < w) woff += ws[j];
        loff[t] = woff + x - v;
    }
    int node = b * 256 + t;
    if (node < N) {
        off[node] = base + loff[t];
        dinv[node] = rsqrtf((float)v + 1.0f);  // +1 self-loop
    }
    __syncthreads();
    hist[t] = 0;  // cursors
    __syncthreads();
    for (int i = t; i < cnt; i += 256) {
        unsigned long long pr = pp[i];
        int dl = (int)(pr >> 32);
        int r = atomicAdd(&hist[dl], 1);
        csr[base + loff[dl] + r] = (int)(unsigned)pr;
    }
}

// ---------------- misc prep ----------------

__global__ __launch_bounds__(256) void graph_count_kernel(const int* __restrict__ batch,
                                                          int* __restrict__ cnt, int N) {
    __shared__ int h[256];
    int t = threadIdx.x;
    h[t] = 0;
    __syncthreads();
    int n = blockIdx.x * 256 + t;
    if (n < N) atomicAdd(&h[batch[n]], 1);
    __syncthreads();
    if (h[t] != 0) atomicAdd(&cnt[t], h[t]);
}

// Y0 = dinv (.) x, bf16; thread i handles 4 floats, row = i >> shift
__global__ __launch_bounds__(256) void prescale_bf16_kernel(const float* __restrict__ in,
                                                            const float* __restrict__ dinv,
                                                            unsigned short* __restrict__ out,
                                                            long n4, int shift) {
    long i = (long)blockIdx.x * 256 + threadIdx.x;
    if (i < n4) {
        float d = dinv[i >> shift];
        float4 v = reinterpret_cast<const float4*>(in)[i];
        ushort4 o;
        o.x = f2bf(d * v.x); o.y = f2bf(d * v.y);
        o.z = f2bf(d * v.z); o.w = f2bf(d * v.w);
        reinterpret_cast<ushort4*>(out)[i] = o;
    }
}

// W [K][256] fp32 -> WT [256][K] bf16
__global__ __launch_bounds__(256) void transpose_w_kernel(const float* __restrict__ W,
                                                          unsigned short* __restrict__ WT,
                                                          int K) {
    int idx = blockIdx.x * 256 + threadIdx.x;
    if (idx < K * 256) {
        int k = idx >> 8, n = idx & 255;
        WT[n * K + k] = f2bf(W[idx]);
    }
}

// ---------------- aggregation: OUT[i] = di * (Y[i] + sum_in Y[s]) ----------
// One wave per node (scalarized); lane owns VEC bf16 cols; 16x-unrolled.
template <int VEC>  // 2 or 4
__global__ __launch_bounds__(256) void aggregate_kernel(
        const unsigned short* __restrict__ Y, unsigned short* __restrict__ OUT,
        const int* __restrict__ off, const int* __restrict__ csr,
        const float* __restrict__ dinv, int N) {
    int node = __builtin_amdgcn_readfirstlane(blockIdx.x * 4 + (threadIdx.x >> 6));
    int lane = threadIdx.x & 63;
    if (node >= N) return;

    float acc[VEC];
    auto loadrow = [&](int s) -> uint2 {
        if constexpr (VEC == 4)
            return reinterpret_cast<const uint2*>(Y)[(size_t)s * 64 + lane];
        else
            return make_uint2(reinterpret_cast<const unsigned*>(Y)[(size_t)s * 64 + lane], 0u);
    };
    auto addrow = [&](uint2 v) {
        acc[0] += bf_lo(v.x);
        acc[1] += bf_hi(v.x);
        if constexpr (VEC == 4) {
            acc[2] += bf_lo(v.y);
            acc[3] += bf_hi(v.y);
        }
    };
    {
        uint2 v = loadrow(node);  // self (Y already dinv-scaled)
        acc[0] = bf_lo(v.x);
        acc[1] = bf_hi(v.x);
        if constexpr (VEC == 4) { acc[2] = bf_lo(v.y); acc[3] = bf_hi(v.y); }
    }
    int e0 = off[node], e1 = off[node + 1];
    int e = e0;
    for (; e + 16 <= e1; e += 16) {
        int s[16];
        uint2 v[16];
        #pragma unroll
        for (int j = 0; j < 16; j++) s[j] = csr[e + j];
        #pragma unroll
        for (int j = 0; j < 16; j++) v[j] = loadrow(s[j]);
        #pragma unroll
        for (int j = 0; j < 16; j++) addrow(v[j]);
    }
    if (e + 8 <= e1) {
        int s[8];
        uint2 v[8];
        #pragma unroll
        for (int j = 0; j < 8; j++) s[j] = csr[e + j];
        #pragma unroll
        for (int j = 0; j < 8; j++) v[j] = loadrow(s[j]);
        #pragma unroll
        for (int j = 0; j < 8; j++) addrow(v[j]);
        e += 8;
    }
    for (; e < e1; e++) addrow(loadrow(csr[e]));

    float di = dinv[node];
    if constexpr (VEC == 4) {
        uint2 o;
        o.x = (unsigned)f2bf(di * acc[0]) | ((unsigned)f2bf(di * acc[1]) << 16);
        o.y = (unsigned)f2bf(di * acc[2]) | ((unsigned)f2bf(di * acc[3]) << 16);
        reinterpret_cast<uint2*>(OUT)[(size_t)node * 64 + lane] = o;
    } else {
        unsigned o = (unsigned)f2bf(di * acc[0]) | ((unsigned)f2bf(di * acc[1]) << 16);
        reinterpret_cast<unsigned*>(OUT)[(size_t)node * 64 + lane] = o;
    }
}

// ---------------- MFMA GEMM ----------------
// C[M][256] = post(relu(A[M][K]@W + bias)), A bf16 row-major, WT=W^T bf16.
// 256 thr / 4 waves, tile 64x256. A (8KB) + W^T k-chunk (32KB) in LDS via
// pre-swizzled global_load_lds; XOR (r&7)<<4 kills stride-128B conflicts.
template <int K, bool SCALE_DINV>
__global__ __launch_bounds__(256) void mfma_gemm_kernel(
        const unsigned short* __restrict__ A, const unsigned short* __restrict__ WT,
        const float* __restrict__ bias, const float* __restrict__ dinv,
        unsigned short* __restrict__ C, int M) {
    __shared__ unsigned short As[64 * 64];
    __shared__ unsigned short Ws[256 * 64];
    const int t = threadIdx.x;
    const int lane = t & 63, w = t >> 6;
    const int r0 = blockIdx.x * 64;
    const int lhi = lane >> 4, l15 = lane & 15;

    f32x4 acc[4][4];
    #pragma unroll
    for (int i = 0; i < 4; i++)
        #pragma unroll
        for (int j = 0; j < 4; j++) acc[i][j] = (f32x4){0.f, 0.f, 0.f, 0.f};

    for (int k0 = 0; k0 < K; k0 += 64) {
        #pragma unroll
        for (int p = 0; p < 2; p++) {  // A: 512 x 16B chunks
            int idx = p * 256 + t;
            int row = idx >> 3;
            int sbyte = ((idx & 7) * 16) ^ ((row & 7) << 4);
            const char* g = (const char*)(A + (size_t)(r0 + row) * K + k0) + sbyte;
            __builtin_amdgcn_global_load_lds(
                (const __attribute__((address_space(1))) void*)g,
                (__attribute__((address_space(3))) void*)((char*)As + idx * 16),
                16, 0, 0);
        }
        #pragma unroll
        for (int q = 0; q < 8; q++) {  // W^T chunk: 2048 x 16B chunks
            int idx = q * 256 + t;
            int col = idx >> 3;
            int sbyte = ((idx & 7) * 16) ^ ((col & 7) << 4);
            const char* g = (const char*)(WT + (size_t)col * K + k0) + sbyte;
            __builtin_amdgcn_global_load_lds(
                (const __attribute__((address_space(1))) void*)g,
                (__attribute__((address_space(3))) void*)((char*)Ws + idx * 16),
                16, 0, 0);
        }
        __syncthreads();
        #pragma unroll
        for (int kk = 0; kk < 64; kk += 32) {
            bf16x8 a[4], b[4];
            int kb = (kk + lhi * 8) * 2;
            #pragma unroll
            for (int mf = 0; mf < 4; mf++) {
                int row = mf * 16 + l15;
                a[mf] = *reinterpret_cast<const bf16x8*>(
                    (const char*)As + row * 128 + (kb ^ ((row & 7) << 4)));
            }
            #pragma unroll
            for (int nf = 0; nf < 4; nf++) {
                int col = w * 64 + nf * 16 + l15;
                b[nf] = *reinterpret_cast<const bf16x8*>(
                    (const char*)Ws + col * 128 + (kb ^ ((col & 7) << 4)));
            }
            #pragma unroll
            for (int mf = 0; mf < 4; mf++)
                #pragma unroll
                for (int nf = 0; nf < 4; nf++)
                    acc[mf][nf] = __builtin_amdgcn_mfma_f32_16x16x32_bf16(
                        a[mf], b[nf], acc[mf][nf], 0, 0, 0);
        }
        __syncthreads();
    }
    #pragma unroll
    for (int mf = 0; mf < 4; mf++) {
        #pragma unroll
        for (int j = 0; j < 4; j++) {
            int m = r0 + mf * 16 + lhi * 4 + j;
            if (m < M) {
                float s = SCALE_DINV ? dinv[m] : 1.0f;
                #pragma unroll
                for (int nf = 0; nf < 4; nf++) {
                    int n = w * 64 + nf * 16 + l15;
                    float v = fmaxf(acc[mf][nf][j] + bias[n], 0.f) * s;
                    C[(size_t)m * 256 + n] = f2bf(v);
                }
            }
        }
    }
}

// ---------------- pooling + head ----------------

__global__ __launch_bounds__(256) void pool_partial_kernel(const unsigned short* __restrict__ H,
                                                           const int* __restrict__ batch,
                                                           float* __restrict__ gsum, int N) {
    int t = threadIdx.x;
    int n0 = blockIdx.x * 256;
    int nend = min(n0 + 256, N);
    int cur = batch[n0];
    float acc = 0.f;
    for (int n = n0; n < nend; n++) {
        int b = batch[n];
        if (b != cur) {
            atomicAdd(&gsum[cur * 256 + t], acc);
            acc = 0.f;
            cur = b;
        }
        acc += __uint_as_float((unsigned)H[(size_t)n * 256 + t] << 16);
    }
    atomicAdd(&gsum[cur * 256 + t], acc);
}

__global__ __launch_bounds__(256) void pool_final_kernel(const float* __restrict__ gsum,
                                                         const int* __restrict__ cnt,
                                                         const float* __restrict__ Wc,
                                                         const float* __restrict__ bc,
                                                         float* __restrict__ out) {
    __shared__ float gm[256];
    int g = blockIdx.x, t = threadIdx.x;
    float inv = 1.0f / fmaxf((float)cnt[g], 1.0f);
    gm[t] = gsum[g * 256 + t] * inv;
    __syncthreads();
    if (t < 200) {
        float acc = bc[t];
        #pragma unroll 8
        for (int k = 0; k < 256; k++) acc += gm[k] * Wc[k * 200 + t];
        out[g * 200 + t] = acc;
    }
}

// ---------------- driver ----------------

extern "C" void kernel_launch(void* const* d_in, const int* in_sizes, int n_in,
                              void* d_out, int out_size, void* d_ws, size_t ws_size,
                              hipStream_t stream) {
    const float* x   = (const float*)d_in[0];
    const int* ei    = (const int*)d_in[1];
    const int* batch = (const int*)d_in[2];
    const float* W1  = (const float*)d_in[4];
    const float* b1  = (const float*)d_in[5];
    const float* W2  = (const float*)d_in[6];
    const float* b2  = (const float*)d_in[7];
    const float* Wc  = (const float*)d_in[8];
    const float* bc  = (const float*)d_in[9];
    float* out = (float*)d_out;

    const int N = in_sizes[2];       // 100000
    const int E = in_sizes[1] / 2;   // 1600000
    const int G = out_size / 200;    // 64
    const int K1 = in_sizes[0] / N;  // 128
    const int Mpad = (N + 63) & ~63; // 100032
    const int NB = (N + 255) >> 8;   // 391 buckets of 256 nodes
    const int* src = ei;
    const int* dst = ei + E;

    char* p = (char*)d_ws;
    auto alloc = [&](size_t bytes) -> char* {
        char* r = p;
        p += (bytes + 255) & ~(size_t)255;
        return r;
    };
    int*   off    = (int*)alloc((size_t)(N + 1) * 4);
    int*   bktCnt = (int*)alloc((size_t)NB * 4);
    int*   bktBase= (int*)alloc((size_t)NB * 4);
    int*   cnt    = (int*)alloc(256 * 4);
    float* dinv   = (float*)alloc((size_t)N * 4);
    float* gsum   = (float*)alloc((size_t)G * 256 * 4);
    int*   csr    = (int*)alloc((size_t)E * 4);
    unsigned long long* pairs = (unsigned long long*)alloc((size_t)NB * BCAP * 8);
    unsigned short* WT1 = (unsigned short*)alloc((size_t)256 * K1 * 2);
    unsigned short* WT2 = (unsigned short*)alloc((size_t)256 * 256 * 2);
    size_t slot = (size_t)Mpad * 256 * 2;   // 51.2 MB
    unsigned short* slotA = (unsigned short*)alloc(slot);  // Y0 -> Y1 -> h2
    unsigned short* slotB = (unsigned short*)alloc(slot);  // a1 -> a2
    unsigned short* Y0 = slotA;
    unsigned short* a1 = slotB;
    unsigned short* Y1 = slotA;
    unsigned short* a2 = slotB;
    unsigned short* h2 = slotA;

    hipMemsetAsync(bktCnt, 0, (size_t)NB * 4, stream);
    hipMemsetAsync(cnt, 0, 256 * 4, stream);
    hipMemsetAsync(gsum, 0, (size_t)G * 256 * 4, stream);

    int blkN = (N + 255) / 256;
    // CSR build (also produces off, dinv)
    bucket_scatter_kernel<<<(E + P1_CHUNK - 1) / P1_CHUNK, 256, 0, stream>>>(
        src, dst, bktCnt, pairs, E, NB);
    bucket_scan_kernel<<<1, 512, 0, stream>>>(bktCnt, bktBase, off, NB, N, E);
    fine_place_kernel<<<NB, 256, 0, stream>>>(pairs, bktCnt, bktBase, off, dinv, csr, N);

    graph_count_kernel<<<blkN, 256, 0, stream>>>(batch, cnt, N);
    long n4 = (long)N * K1 / 4;
    int shift = 31 - __builtin_clz(K1 / 4);  // K1=128 -> 5
    prescale_bf16_kernel<<<(int)((n4 + 255) / 256), 256, 0, stream>>>(x, dinv, Y0, n4, shift);
    transpose_w_kernel<<<(K1 * 256 + 255) / 256, 256, 0, stream>>>(W1, WT1, K1);
    transpose_w_kernel<<<(256 * 256 + 255) / 256, 256, 0, stream>>>(W2, WT2, 256);

    int gemm_blocks = Mpad / 64;
    // layer 1
    aggregate_kernel<2><<<(N + 3) / 4, 256, 0, stream>>>(Y0, a1, off, csr, dinv, N);
    mfma_gemm_kernel<128, true><<<gemm_blocks, 256, 0, stream>>>(a1, WT1, b1, dinv, Y1, N);
    // layer 2
    aggregate_kernel<4><<<(N + 3) / 4, 256, 0, stream>>>(Y1, a2, off, csr, dinv, N);
    mfma_gemm_kernel<256, false><<<gemm_blocks, 256, 0, stream>>>(a2, WT2, b2, nullptr, h2, N);
    // pool + head
    pool_partial_kernel<<<blkN, 256, 0, stream>>>(h2, batch, gsum, N);
    pool_final_kernel<<<G, 256, 0, stream>>>(gsum, cnt, Wc, bc, out);
}